// Round 6
// baseline (4831.695 us; speedup 1.0000x reference)
//
#include <hip/hip_runtime.h>
#include <hip/hip_bf16.h>

typedef unsigned short ushortT;
typedef __attribute__((ext_vector_type(8))) short bf16x8;
typedef __attribute__((ext_vector_type(4))) float f32x4;
typedef __attribute__((ext_vector_type(4))) int i32x4;

#define B_SZ 64
#define T_SZ 512
#define D_SZ 256
#define U_SZ 512
#define M_SZ 64

// ---------- helpers ----------
__device__ __forceinline__ ushortT f2b(float f) {
    __hip_bfloat16 h = __float2bfloat16(f);
    union { __hip_bfloat16 h; ushortT u; } c; c.h = h; return c.u;
}
__device__ __forceinline__ float clip10(float v) {
    return fminf(fmaxf(v, -10.f), 10.f);
}
__device__ __forceinline__ float tanh_fast(float z) {
    float e = __expf(2.f * z);
    return 1.f - 2.f / (e + 1.f);   // inf-safe
}
__device__ __forceinline__ float sigm_fast(float z) {
    return 1.f / (1.f + __expf(-z));
}

// ---------- prep: x -> clipped bf16 ----------
__global__ void prep_xb_k(const float* __restrict__ x, ushortT* __restrict__ xb) {
    const int n4 = (B_SZ * T_SZ * D_SZ) / 4;
    for (int i = blockIdx.x * blockDim.x + threadIdx.x; i < n4; i += gridDim.x * blockDim.x) {
        float4 v = ((const float4*)x)[i];
        ushort4 o;
        o.x = f2b(clip10(v.x));
        o.y = f2b(clip10(v.y));
        o.z = f2b(clip10(v.z));
        o.w = f2b(clip10(v.w));
        ((ushort4*)xb)[i] = o;
    }
}

// ---------- prep: U^T and W^T bf16 (transposed, col-major rows) ----------
// UslT cols: 0..2047 gate U cols, 2048..2111 Ue cols.
// WslT cols: 0..2047 gate W cols, 2048..2111 We cols, 2112..2623 Wm cols.
__global__ void prep_uw_k(const float* __restrict__ Ui, const float* __restrict__ Uf,
                          const float* __restrict__ Uo, const float* __restrict__ Uc,
                          const float* __restrict__ Ue,
                          const float* __restrict__ Wi, const float* __restrict__ Wf,
                          const float* __restrict__ Wo, const float* __restrict__ Wc,
                          const float* __restrict__ We, const float* __restrict__ Wm,
                          ushortT* __restrict__ UslT, ushortT* __restrict__ WslT) {
    const int NU = 2112 * 512;
    const int NW = 2624 * 256;
    for (int i = blockIdx.x * blockDim.x + threadIdx.x; i < NU + NW; i += gridDim.x * blockDim.x) {
        if (i < NU) {
            int c = i >> 9, k = i & 511;
            float v;
            if (c < 2048) {
                int g = c >> 9, u = c & 511;
                const float* U = (g == 0) ? Ui : (g == 1) ? Uf : (g == 2) ? Uo : Uc;
                v = U[k * 512 + u];
            } else {
                v = Ue[k * 64 + (c - 2048)];
            }
            UslT[i] = f2b(v);
        } else {
            int j = i - NU;
            int c = j >> 8, k = j & 255;
            float v;
            if (c < 2048) {
                int g = c >> 9, u = c & 511;
                const float* W = (g == 0) ? Wi : (g == 1) ? Wf : (g == 2) ? Wo : Wc;
                v = W[k * 512 + u];
            } else if (c < 2112) {
                v = We[k * 64 + (c - 2048)];
            } else {
                v = Wm[k * 512 + (c - 2112)];
            }
            WslT[j] = f2b(v);
        }
    }
}

#define MEMF_PB 1096   // floats per batch block (16 rows x 68 + 8 skew)
#define MEMF_ROW 68

// ---------- persistent recurrent kernel ----------
// 256 WGs x 256 threads, 1 block/CU -> all co-resident. Group = bid&7 owns 8
// batches; rank = bid>>3 owns 16 units. All shared state moves through LLC
// (sc0 sc1) -> correct under ANY workgroup->XCD placement (G16).
// Release: pw waves 1,2 store per-wave flags after their own vmcnt drain.
// Acquire: wave 3 ping-pong-polls all 64 group flags, overlapped with phase C.
__global__ __launch_bounds__(256, 1) void xlstm_rec(
    const ushortT* __restrict__ xb,    // [B*T][256] bf16 (clipped)
    const ushortT* __restrict__ UslT,  // [2112][512] bf16
    const ushortT* __restrict__ WslT,  // [2624][256] bf16
    const float* __restrict__ bi_p, const float* __restrict__ bf_p,
    const float* __restrict__ bo_p, const float* __restrict__ bc_p,
    const float* __restrict__ be_p,
    ushortT* __restrict__ Hbuf,        // [2][64][512] bf16
    unsigned* __restrict__ flags,      // [8][64]: flags[grp*64 + rank*2 + w]
    float* __restrict__ out)           // [64][512][512] fp32
{
    const int bid = blockIdx.x, tid = threadIdx.x;
    const int grp = bid & 7, rank = bid >> 3;
    const int wave = tid >> 6, lane = tid & 63;
    const int b0 = grp << 3;     // batch base
    const int u0 = rank << 4;    // unit base

    __shared__ float memF[8 * MEMF_PB];     // c ring: [pb][pu][slot(64)+pad] (thread-private rows)
    __shared__ float g_lds[4][8][16];       // i,f,o,ctilde
    __shared__ float e_lds[8][68];          // raw clipped e-logits (logical idx)
    __shared__ float w_lds[8][72];          // softmax numerators (physical slot)
    __shared__ float zm_lds[8][16];         // x_t @ Wm slice

    for (int i = tid; i < 8 * MEMF_PB; i += 256) memF[i] = 0.f;

    // ---- register-resident weight B-fragments ----
    int cols[2];
    float biasv[2];
#pragma unroll
    for (int nt = 0; nt < 2; ++nt) {
        int j = wave * 32 + nt * 16 + (lane & 15);
        if (j < 64) {
            int g = j >> 4, u = u0 + (j & 15);
            cols[nt] = g * 512 + u;
            biasv[nt] = (g == 0) ? bi_p[u] : (g == 1) ? bf_p[u] : (g == 2) ? bo_p[u] : bc_p[u];
        } else {
            cols[nt] = 2048 + (j - 64);
            biasv[nt] = be_p[j - 64];
        }
    }
    const int koct = (lane >> 4) * 8;
    bf16x8 B1[2][8], B2[2][16], B1m[8];
#pragma unroll
    for (int nt = 0; nt < 2; ++nt) {
        const ushortT* bw = WslT + cols[nt] * 256;
#pragma unroll
        for (int kt = 0; kt < 8; ++kt)
            B1[nt][kt] = *(const bf16x8*)(bw + kt * 32 + koct);
        const ushortT* bu = UslT + cols[nt] * 512;
#pragma unroll
        for (int kt = 0; kt < 16; ++kt)
            B2[nt][kt] = *(const bf16x8*)(bu + kt * 32 + koct);
    }
    if (wave == 1) {   // Wm fragment (zm = x@Wm via MFMA)
        const ushortT* bm = WslT + (2112 + u0 + (lane & 15)) * 256;
#pragma unroll
        for (int kt = 0; kt < 8; ++kt)
            B1m[kt] = *(const bf16x8*)(bm + kt * 32 + koct);
    }

    const int arow = lane & 7;
    const bool is_pw = (tid >= 64 && tid < 192);
    const int pb = (tid - 64) >> 4;
    const int pu = (tid - 64) & 15;

    // ---- prologue: issue a1f loads for t=0 (8 in flight at first phase B) ----
    i32x4 a1f[8];
    {
        const ushortT* xrow = xb + ((b0 + arow) * T_SZ + 0) * D_SZ + koct;
#pragma unroll
        for (int kt = 0; kt < 8; ++kt)
            asm volatile("global_load_dwordx4 %0, %1, off"
                         : "=v"(a1f[kt]) : "v"(xrow + kt * 32));
    }
    __syncthreads();

    for (int t = 0; t < T_SZ; ++t) {
        const int wp = t & 1, rp = wp ^ 1;

        // ---- phase B: h loads (LLC) overlapped with x-MFMAs, then h-MFMAs ----
        i32x4 hfrag[16];
        {
            const ushortT* hrow = Hbuf + (rp << 15) + (b0 + arow) * 512 + koct;
#pragma unroll
            for (int kt = 0; kt < 16; ++kt)
                asm volatile("global_load_dwordx4 %0, %1, off sc0 sc1"
                             : "=v"(hfrag[kt]) : "v"(hrow + kt * 32) : "memory");
        }
        // wait until only the 16 h loads remain -> a1f (and older stores) done
        asm volatile("s_waitcnt vmcnt(16)"
                     : "+v"(a1f[0]), "+v"(a1f[1]), "+v"(a1f[2]), "+v"(a1f[3]),
                       "+v"(a1f[4]), "+v"(a1f[5]), "+v"(a1f[6]), "+v"(a1f[7])
                     :: "memory");
        __builtin_amdgcn_sched_barrier(0);
        f32x4 acc0 = {0.f, 0.f, 0.f, 0.f}, acc1 = {0.f, 0.f, 0.f, 0.f};
        f32x4 acc2 = {0.f, 0.f, 0.f, 0.f};
#pragma unroll
        for (int kt = 0; kt < 8; ++kt) {
            bf16x8 a = __builtin_bit_cast(bf16x8, a1f[kt]);
            acc0 = __builtin_amdgcn_mfma_f32_16x16x32_bf16(a, B1[0][kt], acc0, 0, 0, 0);
            acc1 = __builtin_amdgcn_mfma_f32_16x16x32_bf16(a, B1[1][kt], acc1, 0, 0, 0);
        }
        if (wave == 1) {
#pragma unroll
            for (int kt = 0; kt < 8; ++kt) {
                bf16x8 a = __builtin_bit_cast(bf16x8, a1f[kt]);
                acc2 = __builtin_amdgcn_mfma_f32_16x16x32_bf16(a, B1m[kt], acc2, 0, 0, 0);
            }
        }
        asm volatile("s_waitcnt vmcnt(0)"
                     : "+v"(hfrag[0]), "+v"(hfrag[1]), "+v"(hfrag[2]), "+v"(hfrag[3]),
                       "+v"(hfrag[4]), "+v"(hfrag[5]), "+v"(hfrag[6]), "+v"(hfrag[7]),
                       "+v"(hfrag[8]), "+v"(hfrag[9]), "+v"(hfrag[10]), "+v"(hfrag[11]),
                       "+v"(hfrag[12]), "+v"(hfrag[13]), "+v"(hfrag[14]), "+v"(hfrag[15])
                     :: "memory");
        __builtin_amdgcn_sched_barrier(0);   // rule #18
#pragma unroll
        for (int kt = 0; kt < 16; ++kt) {
            bf16x8 a = __builtin_bit_cast(bf16x8, hfrag[kt]);
            acc0 = __builtin_amdgcn_mfma_f32_16x16x32_bf16(a, B2[0][kt], acc0, 0, 0, 0);
            acc1 = __builtin_amdgcn_mfma_f32_16x16x32_bf16(a, B2[1][kt], acc1, 0, 0, 0);
        }
        // epilogue: C/D layout col=lane&15, row=(lane>>4)*4+i (rows 0..7 in lanes<32)
        if (lane < 32) {
#pragma unroll
            for (int nt = 0; nt < 2; ++nt) {
                int j = wave * 32 + nt * 16 + (lane & 15);
                f32x4 a = nt ? acc1 : acc0;
#pragma unroll
                for (int i = 0; i < 4; ++i) {
                    int b = ((lane >> 4) << 2) + i;
                    float z = clip10(a[i] + biasv[nt]);
                    if (j < 64) {
                        int g = j >> 4;
                        g_lds[g][b][j & 15] = (g == 3) ? tanh_fast(z) : sigm_fast(z);
                    } else {
                        e_lds[b][j - 64] = z;
                    }
                }
            }
            if (wave == 1) {
#pragma unroll
                for (int i = 0; i < 4; ++i)
                    zm_lds[((lane >> 4) << 2) + i][lane & 15] = acc2[i];
            }
        }
        __syncthreads();   // barrier A: gates/e/zm ready

        // ---- phase C: pw (waves 1,2) / ping-pong poll for t+1 (wave 3) ----
        if (is_pw) {
            // max-free softmax numerators (|e|<=10 -> exp safe in fp32)
            const int base = pu * 4;
            const int k0 = t - 1 - base;
            float wv0 = __expf(e_lds[pb][(unsigned)(k0) & 63]);
            float wv1 = __expf(e_lds[pb][(unsigned)(k0 - 1) & 63]);
            float wv2 = __expf(e_lds[pb][(unsigned)(k0 - 2) & 63]);
            float wv3 = __expf(e_lds[pb][(unsigned)(k0 - 3) & 63]);
            float ssum = (wv0 + wv1) + (wv2 + wv3);
#pragma unroll
            for (int d = 1; d < 16; d <<= 1) ssum += __shfl_xor(ssum, d);
            float4 wq = {wv0, wv1, wv2, wv3};
            *(float4*)&w_lds[pb][base] = wq;
            asm volatile("" ::: "memory");   // keep ds_write before ds_reads
            float attn = 0.f;
            const float4* wr = (const float4*)&w_lds[pb][0];
            const float4* mr = (const float4*)&memF[pb * MEMF_PB + pu * MEMF_ROW];
#pragma unroll
            for (int p4 = 0; p4 < 16; ++p4) {
                float4 w4 = wr[p4], m4 = mr[p4];
                attn = fmaf(w4.x, m4.x, attn);
                attn = fmaf(w4.y, m4.y, attn);
                attn = fmaf(w4.z, m4.z, attn);
                attn = fmaf(w4.w, m4.w, attn);
            }
            attn /= ssum;
            float ig = g_lds[0][pb][pu];
            float fg = g_lds[1][pb][pu];
            float og = g_lds[2][pb][pu];
            float ct = g_lds[3][pb][pu];
            float c = fg * (attn + zm_lds[pb][pu]) + ig * ct;
            float h = og * tanh_fast(c);
            memF[pb * MEMF_PB + pu * MEMF_ROW + (t & 63)] = c;
            // h -> LLC, drain, then per-wave flag release
            ushortT hv = f2b(h);
            const ushortT* haddr = Hbuf + (wp << 15) + (b0 + pb) * 512 + u0 + pu;
            asm volatile("global_store_short %0, %1, off sc0 sc1"
                         :: "v"(haddr), "v"((unsigned)hv) : "memory");
            asm volatile("s_waitcnt vmcnt(0)" ::: "memory");   // wave's h acked at LLC
            if (lane == 0) {
                const unsigned* fa = flags + grp * 64 + rank * 2 + (pb >> 2);
                asm volatile("global_store_dword %0, %1, off sc0 sc1"
                             :: "v"(fa), "v"((unsigned)(t + 1)) : "memory");
            }
            out[((b0 + pb) * T_SZ + t) * U_SZ + u0 + pu] = h;   // after flag; never gates release
        } else if (wave == 3 && t + 1 < T_SZ) {
            // ping-pong poll: 2 outstanding flag loads, sample every ~latency/2
            const unsigned tgt = (unsigned)(t + 1);
            const unsigned* fp = flags + grp * 64 + lane;
            bool sat = false;
            unsigned va, vb;
            asm volatile("global_load_dword %0, %2, off sc0 sc1\n\t"
                         "global_load_dword %1, %2, off sc0 sc1"
                         : "=v"(va), "=v"(vb) : "v"(fp) : "memory");
            while (true) {
                asm volatile("s_waitcnt vmcnt(1)" : "+v"(va) :: "memory");
                sat = sat || (va >= tgt);
                if (__all(sat)) break;
                asm volatile("global_load_dword %0, %1, off sc0 sc1"
                             : "=v"(va) : "v"(fp) : "memory");
                asm volatile("s_waitcnt vmcnt(1)" : "+v"(vb) :: "memory");
                sat = sat || (vb >= tgt);
                if (__all(sat)) break;
                asm volatile("global_load_dword %0, %1, off sc0 sc1"
                             : "=v"(vb) : "v"(fp) : "memory");
            }
            asm volatile("s_waitcnt vmcnt(0)" ::: "memory");   // drain leftover poll load
        }

        // ---- all waves: prefetch a1f for t+1 (leaves exactly 8 loads in flight) ----
        {
            const int tn = (t + 1 < T_SZ) ? (t + 1) : t;
            const ushortT* xrow = xb + ((b0 + arow) * T_SZ + tn) * D_SZ + koct;
#pragma unroll
            for (int kt = 0; kt < 8; ++kt)
                asm volatile("global_load_dwordx4 %0, %1, off"
                             : "=v"(a1f[kt]) : "v"(xrow + kt * 32));
        }
        __syncthreads();   // barrier B: pw done, poll done -> h_t confirmed for all
    }
}

// ---------- launch ----------
extern "C" void kernel_launch(void* const* d_in, const int* in_sizes, int n_in,
                              void* d_out, int out_size, void* d_ws, size_t ws_size,
                              hipStream_t stream) {
    const float* x  = (const float*)d_in[0];
    const float* Wi = (const float*)d_in[1];
    const float* Ui = (const float*)d_in[2];
    const float* bi = (const float*)d_in[3];
    const float* Wf = (const float*)d_in[4];
    const float* Uf = (const float*)d_in[5];
    const float* bf = (const float*)d_in[6];
    const float* Wo = (const float*)d_in[7];
    const float* Uo = (const float*)d_in[8];
    const float* bo = (const float*)d_in[9];
    const float* Wc = (const float*)d_in[10];
    const float* Uc = (const float*)d_in[11];
    const float* bc = (const float*)d_in[12];
    const float* Wm = (const float*)d_in[13];
    const float* We = (const float*)d_in[14];
    const float* Ue = (const float*)d_in[15];
    const float* be = (const float*)d_in[16];

    char* ws = (char*)d_ws;
    const size_t off_xb    = 0;
    const size_t off_uslt  = off_xb + (size_t)B_SZ * T_SZ * D_SZ * 2;   // 16,777,216
    const size_t off_wslt  = off_uslt + (size_t)2112 * 512 * 2;         // +2,162,688
    const size_t off_hbuf  = off_wslt + (size_t)2624 * 256 * 2;         // +1,343,488
    const size_t off_flags = off_hbuf + (size_t)2 * 64 * 512 * 2;       // +131,072
    ushortT* xb      = (ushortT*)(ws + off_xb);
    ushortT* UslT    = (ushortT*)(ws + off_uslt);
    ushortT* WslT    = (ushortT*)(ws + off_wslt);
    ushortT* Hb      = (ushortT*)(ws + off_hbuf);
    unsigned* flags  = (unsigned*)(ws + off_flags);
    float* out = (float*)d_out;

    // zero H double-buffer + flags (512 dwords) — re-zeroed every replay
    hipMemsetAsync(ws + off_hbuf, 0, 131072 + 2048, stream);

    prep_xb_k<<<2048, 256, 0, stream>>>(x, xb);
    prep_uw_k<<<2048, 256, 0, stream>>>(Ui, Uf, Uo, Uc, Ue, Wi, Wf, Wo, Wc, We, Wm,
                                        UslT, WslT);

    xlstm_rec<<<dim3(256), dim3(256), 0, stream>>>(
        xb, UslT, WslT, bi, bf, bo, bc, be, Hb, flags, out);
}

// Round 8
// 3689.946 us; speedup vs baseline: 1.3094x; 1.3094x over previous
//
#include <hip/hip_runtime.h>
#include <hip/hip_bf16.h>

typedef unsigned short ushortT;
typedef __attribute__((ext_vector_type(8))) short bf16x8;
typedef __attribute__((ext_vector_type(4))) float f32x4;
typedef __attribute__((ext_vector_type(4))) int i32x4;

#define B_SZ 64
#define T_SZ 512
#define D_SZ 256
#define U_SZ 512
#define M_SZ 64

// ---------- helpers ----------
__device__ __forceinline__ ushortT f2b(float f) {
    __hip_bfloat16 h = __float2bfloat16(f);
    union { __hip_bfloat16 h; ushortT u; } c; c.h = h; return c.u;
}
__device__ __forceinline__ float clip10(float v) {
    return fminf(fmaxf(v, -10.f), 10.f);
}
__device__ __forceinline__ float tanh_fast(float z) {
    float e = __expf(2.f * z);
    return 1.f - 2.f / (e + 1.f);   // inf-safe
}
__device__ __forceinline__ float sigm_fast(float z) {
    return 1.f / (1.f + __expf(-z));
}

// ---------- prep: x -> clipped bf16 ----------
__global__ void prep_xb_k(const float* __restrict__ x, ushortT* __restrict__ xb) {
    const int n4 = (B_SZ * T_SZ * D_SZ) / 4;
    for (int i = blockIdx.x * blockDim.x + threadIdx.x; i < n4; i += gridDim.x * blockDim.x) {
        float4 v = ((const float4*)x)[i];
        ushort4 o;
        o.x = f2b(clip10(v.x));
        o.y = f2b(clip10(v.y));
        o.z = f2b(clip10(v.z));
        o.w = f2b(clip10(v.w));
        ((ushort4*)xb)[i] = o;
    }
}

// ---------- prep: U^T and W^T bf16 (transposed, col-major rows) ----------
// UslT cols: 0..2047 gate U cols, 2048..2111 Ue cols.
// WslT cols: 0..2047 gate W cols, 2048..2111 We cols, 2112..2623 Wm cols.
__global__ void prep_uw_k(const float* __restrict__ Ui, const float* __restrict__ Uf,
                          const float* __restrict__ Uo, const float* __restrict__ Uc,
                          const float* __restrict__ Ue,
                          const float* __restrict__ Wi, const float* __restrict__ Wf,
                          const float* __restrict__ Wo, const float* __restrict__ Wc,
                          const float* __restrict__ We, const float* __restrict__ Wm,
                          ushortT* __restrict__ UslT, ushortT* __restrict__ WslT) {
    const int NU = 2112 * 512;
    const int NW = 2624 * 256;
    for (int i = blockIdx.x * blockDim.x + threadIdx.x; i < NU + NW; i += gridDim.x * blockDim.x) {
        if (i < NU) {
            int c = i >> 9, k = i & 511;
            float v;
            if (c < 2048) {
                int g = c >> 9, u = c & 511;
                const float* U = (g == 0) ? Ui : (g == 1) ? Uf : (g == 2) ? Uo : Uc;
                v = U[k * 512 + u];
            } else {
                v = Ue[k * 64 + (c - 2048)];
            }
            UslT[i] = f2b(v);
        } else {
            int j = i - NU;
            int c = j >> 8, k = j & 255;
            float v;
            if (c < 2048) {
                int g = c >> 9, u = c & 511;
                const float* W = (g == 0) ? Wi : (g == 1) ? Wf : (g == 2) ? Wo : Wc;
                v = W[k * 512 + u];
            } else if (c < 2112) {
                v = We[k * 64 + (c - 2048)];
            } else {
                v = Wm[k * 512 + (c - 2112)];
            }
            WslT[j] = f2b(v);
        }
    }
}

// ---------- flag helpers: ALWAYS LLC-coherent (sc0 sc1) — placement-safe ----------
__device__ __forceinline__ unsigned flag_ld(const unsigned* p) {
    unsigned v;
    asm volatile("global_load_dword %0, %1, off sc0 sc1\n\ts_waitcnt vmcnt(0)"
                 : "=v"(v) : "v"(p) : "memory");
    return v;
}

#define MEMF_PB 1096   // floats per batch block (16 rows x 68 + 8 skew)
#define MEMF_ROW 68

// ---------- persistent recurrent kernel ----------
// 256 WGs x 256 threads, 1 block/CU -> all co-resident. Group = bid&7 owns 8
// batches; rank = bid>>3 owns 16 units. All shared state moves through LLC
// (sc0 sc1) -> correct under ANY workgroup->XCD placement (G16).
// h exchange: cooperative 1x-per-WG LLC load -> XOR-swizzled LDS tile (dbuf).
// Release: per pw-wave flags stored after that wave's own h-store drain.
__global__ __launch_bounds__(256, 1) void xlstm_rec(
    const ushortT* __restrict__ xb,    // [B*T][256] bf16 (clipped)
    const ushortT* __restrict__ UslT,  // [2112][512] bf16
    const ushortT* __restrict__ WslT,  // [2624][256] bf16
    const float* __restrict__ bi_p, const float* __restrict__ bf_p,
    const float* __restrict__ bo_p, const float* __restrict__ bc_p,
    const float* __restrict__ be_p,
    ushortT* __restrict__ Hbuf,        // [2][64][512] bf16
    unsigned* __restrict__ flags,      // [8][64]: flags[grp*64 + rank*2 + (wave-1)]
    float* __restrict__ out)           // [64][512][512] fp32
{
    const int bid = blockIdx.x, tid = threadIdx.x;
    const int grp = bid & 7, rank = bid >> 3;
    const int wave = tid >> 6, lane = tid & 63;
    const int b0 = grp << 3;     // batch base
    const int u0 = rank << 4;    // unit base

    __shared__ float memF[8 * MEMF_PB];     // c ring: [pb][pu][slot(64)+pad] (thread-private rows)
    __shared__ float g_lds[4][8][16];       // i,f,o,ctilde
    __shared__ float e_lds[8][68];          // raw clipped e-logits (logical idx)
    __shared__ float w_lds[8][72];          // softmax numerators (physical slot)
    __shared__ float zm_lds[8][16];         // x_t @ Wm slice
    __shared__ i32x4 hL4[2][512];           // h tile dbuf: [buf][row*64 + (granule^row)]

    for (int i = tid; i < 8 * MEMF_PB; i += 256) memF[i] = 0.f;

    // ---- register-resident weight B-fragments ----
    int cols[2];
    float biasv[2];
#pragma unroll
    for (int nt = 0; nt < 2; ++nt) {
        int j = wave * 32 + nt * 16 + (lane & 15);
        if (j < 64) {
            int g = j >> 4, u = u0 + (j & 15);
            cols[nt] = g * 512 + u;
            biasv[nt] = (g == 0) ? bi_p[u] : (g == 1) ? bf_p[u] : (g == 2) ? bo_p[u] : bc_p[u];
        } else {
            cols[nt] = 2048 + (j - 64);
            biasv[nt] = be_p[j - 64];
        }
    }
    const int koct = (lane >> 4) * 8;
    bf16x8 B1[2][8], B2[2][16], B1m[8];
#pragma unroll
    for (int nt = 0; nt < 2; ++nt) {
        const ushortT* bw = WslT + cols[nt] * 256;
#pragma unroll
        for (int kt = 0; kt < 8; ++kt)
            B1[nt][kt] = *(const bf16x8*)(bw + kt * 32 + koct);
        const ushortT* bu = UslT + cols[nt] * 512;
#pragma unroll
        for (int kt = 0; kt < 16; ++kt)
            B2[nt][kt] = *(const bf16x8*)(bu + kt * 32 + koct);
    }
    if (wave == 1) {   // Wm fragment (zm = x@Wm via MFMA)
        const ushortT* bm = WslT + (2112 + u0 + (lane & 15)) * 256;
#pragma unroll
        for (int kt = 0; kt < 8; ++kt)
            B1m[kt] = *(const bf16x8*)(bm + kt * 32 + koct);
    }

    const int arow = lane & 7;                 // MFMA A-operand batch row
    const bool is_pw = (tid >= 64 && tid < 192);
    const int pb = (tid - 64) >> 4;
    const int pu = (tid - 64) & 15;
    const unsigned* fpoll = flags + grp * 64 + lane;   // one flag per lane
    // cooperative h-staging assignment: wave w loads rows 2w, 2w+1
    const int crow = 2 * wave + (lane >> 5);
    const int gb = (lane & 31) * 2;            // first of 2 granules (16B each)

    __syncthreads();

    for (int t = 0; t < T_SZ; ++t) {
        const int wp = t & 1, rp = wp ^ 1, cur = t & 1;

        // ---- phase A: issue a1f loads; poll flags; issue cooperative h loads ----
        i32x4 a1f[8];
        {
            const ushortT* xrow = xb + ((b0 + arow) * T_SZ + t) * D_SZ + koct;
#pragma unroll
            for (int kt = 0; kt < 8; ++kt)
                asm volatile("global_load_dwordx4 %0, %1, off"
                             : "=v"(a1f[kt]) : "v"(xrow + kt * 32));
        }
        if (t > 0) {
            bool sat = false;
            const unsigned tgt = (unsigned)t;
            while (true) {
                unsigned v = flag_ld(fpoll);   // load + vmcnt(0): also drains a1f/out
                sat = sat || (v >= tgt);
                if (__all(sat)) break;
            }
        }
        i32x4 hl0, hl1;
        {
            const ushortT* csrc = Hbuf + (rp << 15) + (b0 + crow) * 512 + (lane & 31) * 16;
            asm volatile("global_load_dwordx4 %0, %2, off sc0 sc1\n\t"
                         "global_load_dwordx4 %1, %2, off offset:16 sc0 sc1"
                         : "=v"(hl0), "=v"(hl1) : "v"(csrc) : "memory");
        }
        // a1f guaranteed: t>0 via poll's vmcnt(0); t==0 via this vmcnt(2) (8 oldest = a1f)
        asm volatile("s_waitcnt vmcnt(2)"
                     : "+v"(a1f[0]), "+v"(a1f[1]), "+v"(a1f[2]), "+v"(a1f[3]),
                       "+v"(a1f[4]), "+v"(a1f[5]), "+v"(a1f[6]), "+v"(a1f[7])
                     :: "memory");
        __builtin_amdgcn_sched_barrier(0);

        // ---- x-MFMAs while h loads fly ----
        f32x4 acc0 = {0.f, 0.f, 0.f, 0.f}, acc1 = {0.f, 0.f, 0.f, 0.f};
        f32x4 acc2 = {0.f, 0.f, 0.f, 0.f};
#pragma unroll
        for (int kt = 0; kt < 8; ++kt) {
            bf16x8 a = __builtin_bit_cast(bf16x8, a1f[kt]);
            acc0 = __builtin_amdgcn_mfma_f32_16x16x32_bf16(a, B1[0][kt], acc0, 0, 0, 0);
            acc1 = __builtin_amdgcn_mfma_f32_16x16x32_bf16(a, B1[1][kt], acc1, 0, 0, 0);
        }
        if (wave == 1) {
#pragma unroll
            for (int kt = 0; kt < 8; ++kt) {
                bf16x8 a = __builtin_bit_cast(bf16x8, a1f[kt]);
                acc2 = __builtin_amdgcn_mfma_f32_16x16x32_bf16(a, B1m[kt], acc2, 0, 0, 0);
            }
        }

        // ---- h -> LDS (swizzled), S1, h-MFMAs from LDS ----
        asm volatile("s_waitcnt vmcnt(0)"
                     : "+v"(hl0), "+v"(hl1) :: "memory");
        __builtin_amdgcn_sched_barrier(0);
        hL4[cur][crow * 64 + (gb ^ crow)] = hl0;
        hL4[cur][crow * 64 + ((gb + 1) ^ crow)] = hl1;
        __syncthreads();   // S1: h tile ready

#pragma unroll
        for (int kt = 0; kt < 16; ++kt) {
            i32x4 hv = hL4[cur][arow * 64 + ((kt * 4 + (koct >> 3)) ^ arow)];
            bf16x8 a = __builtin_bit_cast(bf16x8, hv);
            acc0 = __builtin_amdgcn_mfma_f32_16x16x32_bf16(a, B2[0][kt], acc0, 0, 0, 0);
            acc1 = __builtin_amdgcn_mfma_f32_16x16x32_bf16(a, B2[1][kt], acc1, 0, 0, 0);
        }

        // ---- epilogue: C/D layout col=lane&15, row=(lane>>4)*4+i (rows 0..7 in lanes<32) ----
        if (lane < 32) {
#pragma unroll
            for (int nt = 0; nt < 2; ++nt) {
                int j = wave * 32 + nt * 16 + (lane & 15);
                f32x4 a = nt ? acc1 : acc0;
#pragma unroll
                for (int i = 0; i < 4; ++i) {
                    int b = ((lane >> 4) << 2) + i;
                    float z = clip10(a[i] + biasv[nt]);
                    if (j < 64) {
                        int g = j >> 4;
                        g_lds[g][b][j & 15] = (g == 3) ? tanh_fast(z) : sigm_fast(z);
                    } else {
                        e_lds[b][j - 64] = z;
                    }
                }
            }
            if (wave == 1) {
#pragma unroll
                for (int i = 0; i < 4; ++i)
                    zm_lds[((lane >> 4) << 2) + i][lane & 15] = acc2[i];
            }
        }
        __syncthreads();   // S2: gates/e/zm ready

        // ---- phase C: pointwise + fast release (waves 1,2) ----
        if (is_pw) {
            // max-free softmax numerators (|e|<=10 -> exp safe in fp32)
            const int base = pu * 4;
            const int k0 = t - 1 - base;
            float wv0 = __expf(e_lds[pb][(unsigned)(k0) & 63]);
            float wv1 = __expf(e_lds[pb][(unsigned)(k0 - 1) & 63]);
            float wv2 = __expf(e_lds[pb][(unsigned)(k0 - 2) & 63]);
            float wv3 = __expf(e_lds[pb][(unsigned)(k0 - 3) & 63]);
            float ssum = (wv0 + wv1) + (wv2 + wv3);
#pragma unroll
            for (int d = 1; d < 16; d <<= 1) ssum += __shfl_xor(ssum, d);
            float4 wq = {wv0, wv1, wv2, wv3};
            *(float4*)&w_lds[pb][base] = wq;
            asm volatile("" ::: "memory");   // keep ds_write before ds_reads
            float attn = 0.f;
            const float4* wr = (const float4*)&w_lds[pb][0];
            const float4* mr = (const float4*)&memF[pb * MEMF_PB + pu * MEMF_ROW];
#pragma unroll
            for (int p4 = 0; p4 < 16; ++p4) {
                float4 w4 = wr[p4], m4 = mr[p4];
                attn = fmaf(w4.x, m4.x, attn);
                attn = fmaf(w4.y, m4.y, attn);
                attn = fmaf(w4.z, m4.z, attn);
                attn = fmaf(w4.w, m4.w, attn);
            }
            attn /= ssum;
            float ig = g_lds[0][pb][pu];
            float fg = g_lds[1][pb][pu];
            float og = g_lds[2][pb][pu];
            float ct = g_lds[3][pb][pu];
            float c = fg * (attn + zm_lds[pb][pu]) + ig * ct;
            float h = og * tanh_fast(c);
            // release chain FIRST: h store -> wave drain -> per-wave flag
            ushortT hv = f2b(h);
            const ushortT* haddr = Hbuf + (wp << 15) + (b0 + pb) * 512 + u0 + pu;
            asm volatile("global_store_short %0, %1, off sc0 sc1"
                         :: "v"(haddr), "v"((unsigned)hv) : "memory");
            asm volatile("s_waitcnt vmcnt(0)" ::: "memory");   // wave's h at LLC
            if (lane == 0) {
                const unsigned* fa = flags + grp * 64 + rank * 2 + (wave - 1);
                asm volatile("global_store_dword %0, %1, off sc0 sc1"
                             :: "v"(fa), "v"((unsigned)(t + 1)) : "memory");
            }
            // off-critical-path writes (drained by next poll's vmcnt(0))
            memF[pb * MEMF_PB + pu * MEMF_ROW + (t & 63)] = c;
            out[((b0 + pb) * T_SZ + t) * U_SZ + u0 + pu] = h;
        }
        // no barrier here: next-iter S1 + flag poll + LDS double-buffering protect
        // all cross-wave structures (memF/w_lds rows are thread-private; g/e/zm
        // are rewritten only after S2 of the NEXT step, which follows next S1).
    }
}

// ---------- launch ----------
extern "C" void kernel_launch(void* const* d_in, const int* in_sizes, int n_in,
                              void* d_out, int out_size, void* d_ws, size_t ws_size,
                              hipStream_t stream) {
    const float* x  = (const float*)d_in[0];
    const float* Wi = (const float*)d_in[1];
    const float* Ui = (const float*)d_in[2];
    const float* bi = (const float*)d_in[3];
    const float* Wf = (const float*)d_in[4];
    const float* Uf = (const float*)d_in[5];
    const float* bf = (const float*)d_in[6];
    const float* Wo = (const float*)d_in[7];
    const float* Uo = (const float*)d_in[8];
    const float* bo = (const float*)d_in[9];
    const float* Wc = (const float*)d_in[10];
    const float* Uc = (const float*)d_in[11];
    const float* bc = (const float*)d_in[12];
    const float* Wm = (const float*)d_in[13];
    const float* We = (const float*)d_in[14];
    const float* Ue = (const float*)d_in[15];
    const float* be = (const float*)d_in[16];

    char* ws = (char*)d_ws;
    const size_t off_xb    = 0;
    const size_t off_uslt  = off_xb + (size_t)B_SZ * T_SZ * D_SZ * 2;   // 16,777,216
    const size_t off_wslt  = off_uslt + (size_t)2112 * 512 * 2;         // +2,162,688
    const size_t off_hbuf  = off_wslt + (size_t)2624 * 256 * 2;         // +1,343,488
    const size_t off_flags = off_hbuf + (size_t)2 * 64 * 512 * 2;       // +131,072
    ushortT* xb      = (ushortT*)(ws + off_xb);
    ushortT* UslT    = (ushortT*)(ws + off_uslt);
    ushortT* WslT    = (ushortT*)(ws + off_wslt);
    ushortT* Hb      = (ushortT*)(ws + off_hbuf);
    unsigned* flags  = (unsigned*)(ws + off_flags);
    float* out = (float*)d_out;

    // zero H double-buffer + flags (8*64 dwords) — re-zeroed every replay
    (void)hipMemsetAsync(ws + off_hbuf, 0, 131072 + 2048, stream);

    prep_xb_k<<<2048, 256, 0, stream>>>(x, xb);
    prep_uw_k<<<2048, 256, 0, stream>>>(Ui, Uf, Uo, Uc, Ue, Wi, Wf, Wo, Wc, We, Wm,
                                        UslT, WslT);

    xlstm_rec<<<dim3(256), dim3(256), 0, stream>>>(
        xb, UslT, WslT, bi, bf, bo, bc, be, Hb, flags, out);
}

// Round 9
// 2303.396 us; speedup vs baseline: 2.0976x; 1.6020x over previous
//
#include <hip/hip_runtime.h>
#include <hip/hip_bf16.h>

typedef unsigned short ushortT;
typedef __attribute__((ext_vector_type(8))) short bf16x8;
typedef __attribute__((ext_vector_type(4))) float f32x4;
typedef __attribute__((ext_vector_type(4))) int i32x4;

#define B_SZ 64
#define T_SZ 512
#define D_SZ 256
#define U_SZ 512
#define M_SZ 64

// ---------- helpers ----------
__device__ __forceinline__ ushortT f2b(float f) {
    __hip_bfloat16 h = __float2bfloat16(f);
    union { __hip_bfloat16 h; ushortT u; } c; c.h = h; return c.u;
}
__device__ __forceinline__ float clip10(float v) {
    return fminf(fmaxf(v, -10.f), 10.f);
}
__device__ __forceinline__ float tanh_fast(float z) {
    float e = __expf(2.f * z);
    return 1.f - 2.f / (e + 1.f);   // inf-safe
}
__device__ __forceinline__ float sigm_fast(float z) {
    return 1.f / (1.f + __expf(-z));
}

// ---------- prep: x -> clipped bf16 ----------
__global__ void prep_xb_k(const float* __restrict__ x, ushortT* __restrict__ xb) {
    const int n4 = (B_SZ * T_SZ * D_SZ) / 4;
    for (int i = blockIdx.x * blockDim.x + threadIdx.x; i < n4; i += gridDim.x * blockDim.x) {
        float4 v = ((const float4*)x)[i];
        ushort4 o;
        o.x = f2b(clip10(v.x));
        o.y = f2b(clip10(v.y));
        o.z = f2b(clip10(v.z));
        o.w = f2b(clip10(v.w));
        ((ushort4*)xb)[i] = o;
    }
}

// ---------- prep: U^T and W^T bf16 (transposed, col-major rows) ----------
// UslT cols: 0..2047 gate U cols, 2048..2111 Ue cols.
// WslT cols: 0..2047 gate W cols, 2048..2111 We cols, 2112..2623 Wm cols.
__global__ void prep_uw_k(const float* __restrict__ Ui, const float* __restrict__ Uf,
                          const float* __restrict__ Uo, const float* __restrict__ Uc,
                          const float* __restrict__ Ue,
                          const float* __restrict__ Wi, const float* __restrict__ Wf,
                          const float* __restrict__ Wo, const float* __restrict__ Wc,
                          const float* __restrict__ We, const float* __restrict__ Wm,
                          ushortT* __restrict__ UslT, ushortT* __restrict__ WslT) {
    const int NU = 2112 * 512;
    const int NW = 2624 * 256;
    for (int i = blockIdx.x * blockDim.x + threadIdx.x; i < NU + NW; i += gridDim.x * blockDim.x) {
        if (i < NU) {
            int c = i >> 9, k = i & 511;
            float v;
            if (c < 2048) {
                int g = c >> 9, u = c & 511;
                const float* U = (g == 0) ? Ui : (g == 1) ? Uf : (g == 2) ? Uo : Uc;
                v = U[k * 512 + u];
            } else {
                v = Ue[k * 64 + (c - 2048)];
            }
            UslT[i] = f2b(v);
        } else {
            int j = i - NU;
            int c = j >> 8, k = j & 255;
            float v;
            if (c < 2048) {
                int g = c >> 9, u = c & 511;
                const float* W = (g == 0) ? Wi : (g == 1) ? Wf : (g == 2) ? Wo : Wc;
                v = W[k * 512 + u];
            } else if (c < 2112) {
                v = We[k * 64 + (c - 2048)];
            } else {
                v = Wm[k * 512 + (c - 2112)];
            }
            WslT[j] = f2b(v);
        }
    }
}

#define MEMF_PB 1096   // floats per batch block (16 rows x 68 + 8 skew)
#define MEMF_ROW 68

// ---------- persistent recurrent kernel ----------
// 256 WGs x 256 threads, 1 block/CU -> all co-resident. Group = bid&7 owns 8
// batches; rank = bid>>3 owns 16 units. h exchange is SELF-VALIDATING: each h
// value is stored as (tag<<16 | bf16h) u32 through the LLC (sc0 sc1). The
// consumer polls the tagged tile directly — no flags, no producer drain, ONE
// LLC leg per step. Tag==t check is race-free: for tag t+2 to overwrite this
// parity buffer, every WG (incl. this one) must already have passed its step-t
// poll (all-to-all dependence through h). Placement-independent (G16-safe).
__global__ __launch_bounds__(256, 1) void xlstm_rec(
    const ushortT* __restrict__ xb,    // [B*T][256] bf16 (clipped)
    const ushortT* __restrict__ UslT,  // [2112][512] bf16
    const ushortT* __restrict__ WslT,  // [2624][256] bf16
    const float* __restrict__ bi_p, const float* __restrict__ bf_p,
    const float* __restrict__ bo_p, const float* __restrict__ bc_p,
    const float* __restrict__ be_p,
    unsigned* __restrict__ Hbuf32,     // [2][64][512] u32 tagged h
    float* __restrict__ out)           // [64][512][512] fp32
{
    const int bid = blockIdx.x, tid = threadIdx.x;
    const int grp = bid & 7, rank = bid >> 3;
    const int wave = tid >> 6, lane = tid & 63;
    const int b0 = grp << 3;     // batch base
    const int u0 = rank << 4;    // unit base

    __shared__ float memF[8 * MEMF_PB];     // c ring: [pb][pu][slot(64)+pad] (thread-private rows)
    __shared__ float g_lds[4][8][16];       // i,f,o,ctilde
    __shared__ float e_lds[8][68];          // raw clipped e-logits (logical idx)
    __shared__ float w_lds[8][72];          // softmax numerators (physical slot)
    __shared__ float zm_lds[8][16];         // x_t @ Wm slice
    __shared__ ushortT hLb[8][520];         // h tile bf16, padded stride (1040B)

    for (int i = tid; i < 8 * MEMF_PB; i += 256) memF[i] = 0.f;

    // ---- register-resident weight B-fragments ----
    int cols[2];
    float biasv[2];
#pragma unroll
    for (int nt = 0; nt < 2; ++nt) {
        int j = wave * 32 + nt * 16 + (lane & 15);
        if (j < 64) {
            int g = j >> 4, u = u0 + (j & 15);
            cols[nt] = g * 512 + u;
            biasv[nt] = (g == 0) ? bi_p[u] : (g == 1) ? bf_p[u] : (g == 2) ? bo_p[u] : bc_p[u];
        } else {
            cols[nt] = 2048 + (j - 64);
            biasv[nt] = be_p[j - 64];
        }
    }
    const int koct = (lane >> 4) * 8;
    bf16x8 B1[2][8], B2[2][16], B1m[8];
#pragma unroll
    for (int nt = 0; nt < 2; ++nt) {
        const ushortT* bw = WslT + cols[nt] * 256;
#pragma unroll
        for (int kt = 0; kt < 8; ++kt)
            B1[nt][kt] = *(const bf16x8*)(bw + kt * 32 + koct);
        const ushortT* bu = UslT + cols[nt] * 512;
#pragma unroll
        for (int kt = 0; kt < 16; ++kt)
            B2[nt][kt] = *(const bf16x8*)(bu + kt * 32 + koct);
    }
    if (wave == 1) {   // Wm fragment (zm = x@Wm via MFMA)
        const ushortT* bm = WslT + (2112 + u0 + (lane & 15)) * 256;
#pragma unroll
        for (int kt = 0; kt < 8; ++kt)
            B1m[kt] = *(const bf16x8*)(bm + kt * 32 + koct);
    }

    const int arow = lane & 7;                 // MFMA A-operand batch row
    const bool is_pw = (tid >= 64 && tid < 192);
    const int pb = (tid - 64) >> 4;
    const int pu = (tid - 64) & 15;
    // cooperative tagged-h fetch: wave w owns rows 2w (lanes<32), 2w+1 (lanes>=32)
    const int prow = 2 * wave + (lane >> 5);
    const int pcol = (lane & 31) * 16;         // 16 u32 units per lane

    __syncthreads();

    for (int t = 0; t < T_SZ; ++t) {
        const int par = t & 1, wpar = (t + 1) & 1;

        // ---- phase A: issue a1f x-fragment loads (overlap with poll) ----
        i32x4 a1f[8];
        {
            const ushortT* xrow = xb + ((b0 + arow) * T_SZ + t) * D_SZ + koct;
#pragma unroll
            for (int kt = 0; kt < 8; ++kt)
                asm volatile("global_load_dwordx4 %0, %1, off"
                             : "=v"(a1f[kt]) : "v"(xrow + kt * 32));
        }

        // ---- phase B: poll tagged h tile (own 2 rows) until all tags == t ----
        const unsigned* hsrc = Hbuf32 + (par << 15) + (b0 + prow) * 512 + pcol;
        const unsigned T16 = ((unsigned)t) << 16;
        i32x4 g0, g1, g2, g3;
        while (true) {
            asm volatile("global_load_dwordx4 %0, %4, off sc0 sc1\n\t"
                         "global_load_dwordx4 %1, %4, off offset:16 sc0 sc1\n\t"
                         "global_load_dwordx4 %2, %4, off offset:32 sc0 sc1\n\t"
                         "global_load_dwordx4 %3, %4, off offset:48 sc0 sc1\n\t"
                         "s_waitcnt vmcnt(0)"
                         : "=v"(g0), "=v"(g1), "=v"(g2), "=v"(g3)
                         : "v"(hsrc) : "memory");
            unsigned d = (((unsigned)g0[0] ^ T16) | ((unsigned)g0[1] ^ T16)) |
                         (((unsigned)g0[2] ^ T16) | ((unsigned)g0[3] ^ T16));
            d |= (((unsigned)g1[0] ^ T16) | ((unsigned)g1[1] ^ T16)) |
                 (((unsigned)g1[2] ^ T16) | ((unsigned)g1[3] ^ T16));
            d |= (((unsigned)g2[0] ^ T16) | ((unsigned)g2[1] ^ T16)) |
                 (((unsigned)g2[2] ^ T16) | ((unsigned)g2[3] ^ T16));
            d |= (((unsigned)g3[0] ^ T16) | ((unsigned)g3[1] ^ T16)) |
                 (((unsigned)g3[2] ^ T16) | ((unsigned)g3[3] ^ T16));
            if (__all((d & 0xFFFF0000u) == 0u)) break;
        }
        __builtin_amdgcn_sched_barrier(0);

        // ---- phase C: strip tags, pack bf16 pairs, stage into LDS ----
        {
            unsigned p0 = ((unsigned)g0[0] & 0xFFFFu) | ((unsigned)g0[1] << 16);
            unsigned p1 = ((unsigned)g0[2] & 0xFFFFu) | ((unsigned)g0[3] << 16);
            unsigned p2 = ((unsigned)g1[0] & 0xFFFFu) | ((unsigned)g1[1] << 16);
            unsigned p3 = ((unsigned)g1[2] & 0xFFFFu) | ((unsigned)g1[3] << 16);
            unsigned p4 = ((unsigned)g2[0] & 0xFFFFu) | ((unsigned)g2[1] << 16);
            unsigned p5 = ((unsigned)g2[2] & 0xFFFFu) | ((unsigned)g2[3] << 16);
            unsigned p6 = ((unsigned)g3[0] & 0xFFFFu) | ((unsigned)g3[1] << 16);
            unsigned p7 = ((unsigned)g3[2] & 0xFFFFu) | ((unsigned)g3[3] << 16);
            i32x4 P0 = {(int)p0, (int)p1, (int)p2, (int)p3};
            i32x4 P1 = {(int)p4, (int)p5, (int)p6, (int)p7};
            *(i32x4*)&hLb[prow][pcol] = P0;
            *(i32x4*)&hLb[prow][pcol + 8] = P1;
        }
        // x-MFMAs before S1 (a1f drained by poll's vmcnt(0))
        f32x4 acc0 = {0.f, 0.f, 0.f, 0.f}, acc1 = {0.f, 0.f, 0.f, 0.f};
        f32x4 acc2 = {0.f, 0.f, 0.f, 0.f};
#pragma unroll
        for (int kt = 0; kt < 8; ++kt) {
            bf16x8 a = __builtin_bit_cast(bf16x8, a1f[kt]);
            acc0 = __builtin_amdgcn_mfma_f32_16x16x32_bf16(a, B1[0][kt], acc0, 0, 0, 0);
            acc1 = __builtin_amdgcn_mfma_f32_16x16x32_bf16(a, B1[1][kt], acc1, 0, 0, 0);
        }
        if (wave == 1) {
#pragma unroll
            for (int kt = 0; kt < 8; ++kt) {
                bf16x8 a = __builtin_bit_cast(bf16x8, a1f[kt]);
                acc2 = __builtin_amdgcn_mfma_f32_16x16x32_bf16(a, B1m[kt], acc2, 0, 0, 0);
            }
        }
        __syncthreads();   // S1: h tile staged

        // ---- phase D: h-MFMAs from LDS ----
#pragma unroll
        for (int kt = 0; kt < 16; ++kt) {
            bf16x8 a = *(const bf16x8*)&hLb[arow][kt * 32 + koct];
            acc0 = __builtin_amdgcn_mfma_f32_16x16x32_bf16(a, B2[0][kt], acc0, 0, 0, 0);
            acc1 = __builtin_amdgcn_mfma_f32_16x16x32_bf16(a, B2[1][kt], acc1, 0, 0, 0);
        }

        // ---- phase E: epilogue (C/D: col=lane&15, row=(lane>>4)*4+i; rows 0..7 in lanes<32) ----
        if (lane < 32) {
#pragma unroll
            for (int nt = 0; nt < 2; ++nt) {
                int j = wave * 32 + nt * 16 + (lane & 15);
                f32x4 a = nt ? acc1 : acc0;
#pragma unroll
                for (int i = 0; i < 4; ++i) {
                    int b = ((lane >> 4) << 2) + i;
                    float z = clip10(a[i] + biasv[nt]);
                    if (j < 64) {
                        int g = j >> 4;
                        g_lds[g][b][j & 15] = (g == 3) ? tanh_fast(z) : sigm_fast(z);
                    } else {
                        e_lds[b][j - 64] = z;
                    }
                }
            }
            if (wave == 1) {
#pragma unroll
                for (int i = 0; i < 4; ++i)
                    zm_lds[((lane >> 4) << 2) + i][lane & 15] = acc2[i];
            }
        }
        __syncthreads();   // S2: gates/e/zm ready

        // ---- phase F: pointwise + tagged-h release (waves 1,2) ----
        if (is_pw) {
            // max-free softmax numerators (|e|<=10 -> exp safe in fp32)
            const int base = pu * 4;
            const int k0 = t - 1 - base;
            float wv0 = __expf(e_lds[pb][(unsigned)(k0) & 63]);
            float wv1 = __expf(e_lds[pb][(unsigned)(k0 - 1) & 63]);
            float wv2 = __expf(e_lds[pb][(unsigned)(k0 - 2) & 63]);
            float wv3 = __expf(e_lds[pb][(unsigned)(k0 - 3) & 63]);
            float ssum = (wv0 + wv1) + (wv2 + wv3);
#pragma unroll
            for (int d = 1; d < 16; d <<= 1) ssum += __shfl_xor(ssum, d);
            float4 wq = {wv0, wv1, wv2, wv3};
            *(float4*)&w_lds[pb][base] = wq;
            asm volatile("" ::: "memory");   // keep ds_write before ds_reads
            float attn = 0.f;
            const float4* wr = (const float4*)&w_lds[pb][0];
            const float4* mr = (const float4*)&memF[pb * MEMF_PB + pu * MEMF_ROW];
#pragma unroll
            for (int p4i = 0; p4i < 16; ++p4i) {
                float4 w4 = wr[p4i], m4 = mr[p4i];
                attn = fmaf(w4.x, m4.x, attn);
                attn = fmaf(w4.y, m4.y, attn);
                attn = fmaf(w4.z, m4.z, attn);
                attn = fmaf(w4.w, m4.w, attn);
            }
            attn /= ssum;
            float ig = g_lds[0][pb][pu];
            float fg = g_lds[1][pb][pu];
            float og = g_lds[2][pb][pu];
            float ct = g_lds[3][pb][pu];
            float c = fg * (attn + zm_lds[pb][pu]) + ig * ct;
            float h = og * tanh_fast(c);
            // tagged-h release: single store, NO drain, NO flag
            unsigned tagval = (((unsigned)(t + 1)) << 16) | (unsigned)f2b(h);
            const unsigned* haddr = Hbuf32 + (wpar << 15) + (b0 + pb) * 512 + u0 + pu;
            asm volatile("global_store_dword %0, %1, off sc0 sc1"
                         :: "v"(haddr), "v"(tagval) : "memory");
            // off-critical-path writes (drained by next poll's vmcnt(0))
            memF[pb * MEMF_PB + pu * MEMF_ROW + (t & 63)] = c;
            out[((b0 + pb) * T_SZ + t) * U_SZ + u0 + pu] = h;
        }
        // no end barrier: S2(t) separates D(t) readers of hLb from C(t+1)
        // writers (C' only reachable after S2'... after loop-back), and F(t)
        // readers of g/e/zm finish before their wave reaches S1(t+1), which
        // precedes any E(t+1) writer. memF/w_lds rows are wave-private.
    }
}

// ---------- launch ----------
extern "C" void kernel_launch(void* const* d_in, const int* in_sizes, int n_in,
                              void* d_out, int out_size, void* d_ws, size_t ws_size,
                              hipStream_t stream) {
    const float* x  = (const float*)d_in[0];
    const float* Wi = (const float*)d_in[1];
    const float* Ui = (const float*)d_in[2];
    const float* bi = (const float*)d_in[3];
    const float* Wf = (const float*)d_in[4];
    const float* Uf = (const float*)d_in[5];
    const float* bf = (const float*)d_in[6];
    const float* Wo = (const float*)d_in[7];
    const float* Uo = (const float*)d_in[8];
    const float* bo = (const float*)d_in[9];
    const float* Wc = (const float*)d_in[10];
    const float* Uc = (const float*)d_in[11];
    const float* bc = (const float*)d_in[12];
    const float* Wm = (const float*)d_in[13];
    const float* We = (const float*)d_in[14];
    const float* Ue = (const float*)d_in[15];
    const float* be = (const float*)d_in[16];

    char* ws = (char*)d_ws;
    const size_t off_xb    = 0;
    const size_t off_uslt  = off_xb + (size_t)B_SZ * T_SZ * D_SZ * 2;   // 16,777,216
    const size_t off_wslt  = off_uslt + (size_t)2112 * 512 * 2;         // +2,162,688
    const size_t off_hbuf  = off_wslt + (size_t)2624 * 256 * 2;         // +1,343,488
    ushortT* xb       = (ushortT*)(ws + off_xb);
    ushortT* UslT     = (ushortT*)(ws + off_uslt);
    ushortT* WslT     = (ushortT*)(ws + off_wslt);
    unsigned* Hbuf32  = (unsigned*)(ws + off_hbuf);   // 2*64*512*4 = 262,144 B
    float* out = (float*)d_out;

    // zero tagged-h double buffer (tags -> 0) — re-zeroed every replay
    (void)hipMemsetAsync(ws + off_hbuf, 0, 262144, stream);

    prep_xb_k<<<2048, 256, 0, stream>>>(x, xb);
    prep_uw_k<<<2048, 256, 0, stream>>>(Ui, Uf, Uo, Uc, Ue, Wi, Wf, Wo, Wc, We, Wm,
                                        UslT, WslT);

    xlstm_rec<<<dim3(256), dim3(256), 0, stream>>>(
        xb, UslT, WslT, bi, bf, bo, bc, be, Hbuf32, out);
}